// Round 3
// baseline (684.508 us; speedup 1.0000x reference)
//
#include <hip/hip_runtime.h>
#include <hip/hip_bf16.h>
#include <stdint.h>

#define IN_DIM 256
#define AGG_BLOCKS 2048

typedef __attribute__((ext_vector_type(8))) short short8;
typedef __attribute__((ext_vector_type(4))) float f32x4;

__device__ __forceinline__ float bf2f(unsigned short u){
  return __uint_as_float(((unsigned int)u) << 16);
}
__device__ __forceinline__ unsigned short f2bf(float f){
  unsigned int u = __float_as_uint(f);
  u = u + 0x7FFFu + ((u >> 16) & 1u);
  return (unsigned short)(u >> 16);
}

// ---------------- edge dtype detection (int64 vs int32) ----------------
__global__ void k_detect(const void* ei, long long E, int N, int* flag){
  __shared__ int bad;
  if (threadIdx.x == 0) bad = 0;
  __syncthreads();
  const long long* p = (const long long*)ei;
  long long stride = E / 1024; if (stride < 1) stride = 1;
  for (int i = threadIdx.x; i < 1024; i += blockDim.x){
    long long idx = (long long)i * stride;
    if (idx >= E) break;
    long long v = p[idx];
    if (v < 0 || v >= (long long)N) atomicOr(&bad, 1);
  }
  __syncthreads();
  if (threadIdx.x == 0) flag[0] = bad ? 0 : 1;  // 1 = int64 data
}

__device__ __forceinline__ int edge_at(const void* ei, long long i, int f64){
  if (f64) return (int)((const long long*)ei)[i];
  return ((const int*)ei)[i];
}

// ---------------- CSR build ----------------
__global__ void k_hist(const void* ei, long long E, const int* flag, int* cnt){
  long long e = (long long)blockIdx.x * blockDim.x + threadIdx.x;
  if (e < E){
    int f = flag[0];
    int d = edge_at(ei, E + e, f);
    atomicAdd(&cnt[d], 1);
  }
}

// scan1 also produces dinv and zeroes fill
__global__ void k_scan1(const int* cnt, int* rs, int* bsum, float* dinv, int* fill, int N){
  __shared__ int sh[1024];
  int i = blockIdx.x * 1024 + threadIdx.x;
  int v = (i < N) ? cnt[i] : 0;
  sh[threadIdx.x] = v;
  __syncthreads();
  for (int o = 1; o < 1024; o <<= 1){
    int x = (threadIdx.x >= o) ? sh[threadIdx.x - o] : 0;
    __syncthreads();
    sh[threadIdx.x] += x;
    __syncthreads();
  }
  if (i < N){
    rs[i] = sh[threadIdx.x] - v;          // exclusive
    dinv[i] = rsqrtf((float)v + 1.0f);
    fill[i] = 0;
  }
  if (threadIdx.x == 1023) bsum[blockIdx.x] = sh[1023];
}

// scan2 also zeroes BN accumulators
__global__ void k_scan2(const int* bsum, int* boff, int nb, int* rs, int N,
                        float* sums, float* sqs){
  __shared__ int sh[128];
  int t = threadIdx.x;
  int v = (t < nb) ? bsum[t] : 0;
  sh[t] = v;
  __syncthreads();
  for (int o = 1; o < 128; o <<= 1){
    int x = (t >= o) ? sh[t - o] : 0;
    __syncthreads();
    sh[t] += x;
    __syncthreads();
  }
  boff[t] = sh[t] - v;
  if (t == 127) rs[N] = sh[127];
  sums[t] = 0.f; sums[t + 128] = 0.f;
  sqs[t]  = 0.f; sqs[t + 128]  = 0.f;
}

__global__ void k_scan3(int* rs, const int* boff, int N){
  int i = blockIdx.x * 1024 + threadIdx.x;
  if (i < N) rs[i] += boff[blockIdx.x];
}

__global__ void k_scatter(const void* ei, long long E, const int* flag, const int* rs,
                          int* fill, int* csrc){
  long long e = (long long)blockIdx.x * blockDim.x + threadIdx.x;
  if (e < E){
    int f = flag[0];
    int s = edge_at(ei, e, f);
    int d = edge_at(ei, E + e, f);
    int pos = atomicAdd(&fill[d], 1);
    csrc[rs[d] + pos] = s;
  }
}

// ---------------- fused conversions: xb=bf16(x), W1t, W2t transposed bf16 ----------------
__global__ void k_prep(const float* __restrict__ x, ushort* __restrict__ xb,
                       const float* __restrict__ W1, ushort* __restrict__ W1t,
                       const float* __restrict__ W2, ushort* __restrict__ W2t,
                       int N, int NP){
  int idx = blockIdx.x * 256 + threadIdx.x;
  int nxq = NP * 64;                        // ushort4 groups in xb
  if (idx < nxq){
    int row = idx >> 6, q = idx & 63;
    ushort4 o = {0, 0, 0, 0};
    if (row < N){
      float4 v = ((const float4*)x)[(size_t)row * 64 + q];
      o.x = f2bf(v.x); o.y = f2bf(v.y); o.z = f2bf(v.z); o.w = f2bf(v.w);
    }
    ((ushort4*)xb)[idx] = o;
  } else {
    int j = idx - nxq;
    if (j < 256 * 256){                     // W1t[n*256+k] = W1[k*256+n]
      int n = j >> 8, k = j & 255;
      W1t[j] = f2bf(W1[(size_t)k * 256 + n]);
    } else {
      j -= 65536;
      if (j < 128 * 256){                   // W2t[n*256+k] = W2[k*128+n]
        int n = j >> 8, k = j & 255;
        W2t[j] = f2bf(W2[(size_t)k * 128 + n]);
      }
    }
  }
}

// ---------------- GEMM: C[M,Nc] = dinv[row] * (A[M,256] @ Bt[Nc,256]^T)  bf16 out ----------------
__global__ __launch_bounds__(256) void k_gemm(const ushort* __restrict__ A,
                                              const ushort* __restrict__ Bt,
                                              ushort* __restrict__ C,
                                              const float* __restrict__ dinv,
                                              int N, int Nc){
  __shared__ ushort As[128 * 64];
  __shared__ ushort Bs[128 * 64];
  const int tid = threadIdx.x;
  const int wave = tid >> 6, lane = tid & 63;
  const long long row0 = (long long)blockIdx.x * 128;
  const int col0 = blockIdx.y * 128;
  const int lr = lane >> 3, lc = lane & 7;
  const int mrow = ((wave & 1) << 6) + (lane & 15);
  const int ncol = ((wave >> 1) << 6) + (lane & 15);

  f32x4 acc[4][4];
  #pragma unroll
  for (int i = 0; i < 4; ++i)
    #pragma unroll
    for (int j = 0; j < 4; ++j)
      acc[i][j] = (f32x4){0.f, 0.f, 0.f, 0.f};

  const ushort* gA = A + (row0 + wave * 32 + lr) * 256 + lc * 8;
  const ushort* gB = Bt + ((long long)(col0 + wave * 32 + lr)) * 256 + lc * 8;
  ushort* lA = As + wave * 2048;
  ushort* lB = Bs + wave * 2048;

  #pragma unroll
  for (int kt = 0; kt < 4; ++kt){
    #pragma unroll
    for (int i = 0; i < 4; ++i){
      __builtin_amdgcn_global_load_lds(
          (const __attribute__((address_space(1))) void*)(gA + kt * 64 + i * 8 * 256),
          (__attribute__((address_space(3))) void*)(lA + i * 512), 16, 0, 0);
      __builtin_amdgcn_global_load_lds(
          (const __attribute__((address_space(1))) void*)(gB + kt * 64 + i * 8 * 256),
          (__attribute__((address_space(3))) void*)(lB + i * 512), 16, 0, 0);
    }
    __syncthreads();
    #pragma unroll
    for (int ks = 0; ks < 2; ++ks){
      const int kb = ks * 32 + ((lane >> 4) << 3);
      short8 af[4], bfv[4];
      #pragma unroll
      for (int i = 0; i < 4; ++i) af[i] = *(const short8*)(As + (mrow + i * 16) * 64 + kb);
      #pragma unroll
      for (int j = 0; j < 4; ++j) bfv[j] = *(const short8*)(Bs + (ncol + j * 16) * 64 + kb);
      #pragma unroll
      for (int i = 0; i < 4; ++i)
        #pragma unroll
        for (int j = 0; j < 4; ++j)
          acc[i][j] = __builtin_amdgcn_mfma_f32_16x16x32_bf16(af[i], bfv[j], acc[i][j], 0, 0, 0);
    }
    __syncthreads();
  }

  const int rbase = ((wave & 1) << 6) + ((lane >> 4) << 2);
  const int cb = col0 + ((wave >> 1) << 6) + (lane & 15);
  #pragma unroll
  for (int i = 0; i < 4; ++i)
    #pragma unroll
    for (int r = 0; r < 4; ++r){
      long long row = row0 + rbase + i * 16 + r;
      float sc = (row < N) ? dinv[row] : 0.f;
      #pragma unroll
      for (int j = 0; j < 4; ++j)
        C[row * Nc + cb + j * 16] = f2bf(sc * acc[i][j][r]);
    }
}

// ---------------- aggregation 1: persistent waves, readlane-broadcast CSR, bf16 out ----------------
__global__ __launch_bounds__(256) void k_agg1(const ushort* __restrict__ hs, const int* __restrict__ rs,
    const int* __restrict__ csrc, const float* __restrict__ dinv, const float* __restrict__ b1,
    ushort* __restrict__ h1, int N){
  const int lane = threadIdx.x & 63;
  const int wid = (blockIdx.x * 256 + threadIdx.x) >> 6;
  const int nw = (AGG_BLOCKS * 256) >> 6;
  const float4 bb = ((const float4*)b1)[lane];

  for (int n = wid; n < N; n += nw){
    const ushort4* selfp = (const ushort4*)(hs + (size_t)n * 256);
    ushort4 sv = selfp[lane];
    float a0 = bf2f(sv.x), a1 = bf2f(sv.y), a2 = bf2f(sv.z), a3 = bf2f(sv.w);
    int e0 = rs[n], deg = rs[n + 1] - e0;

    for (int c = 0; c < deg; c += 64){
      int chunk = deg - c; if (chunk > 64) chunk = 64;
      int myc = 0;
      if (lane < chunk) myc = csrc[e0 + c + lane];
      int j = 0;
      for (; j + 8 <= chunk; j += 8){
        int s0 = __builtin_amdgcn_readlane(myc, j);
        int s1 = __builtin_amdgcn_readlane(myc, j + 1);
        int s2 = __builtin_amdgcn_readlane(myc, j + 2);
        int s3 = __builtin_amdgcn_readlane(myc, j + 3);
        int s4 = __builtin_amdgcn_readlane(myc, j + 4);
        int s5 = __builtin_amdgcn_readlane(myc, j + 5);
        int s6 = __builtin_amdgcn_readlane(myc, j + 6);
        int s7 = __builtin_amdgcn_readlane(myc, j + 7);
        ushort4 v0 = ((const ushort4*)(hs + (size_t)s0 * 256))[lane];
        ushort4 v1 = ((const ushort4*)(hs + (size_t)s1 * 256))[lane];
        ushort4 v2 = ((const ushort4*)(hs + (size_t)s2 * 256))[lane];
        ushort4 v3 = ((const ushort4*)(hs + (size_t)s3 * 256))[lane];
        ushort4 v4 = ((const ushort4*)(hs + (size_t)s4 * 256))[lane];
        ushort4 v5 = ((const ushort4*)(hs + (size_t)s5 * 256))[lane];
        ushort4 v6 = ((const ushort4*)(hs + (size_t)s6 * 256))[lane];
        ushort4 v7 = ((const ushort4*)(hs + (size_t)s7 * 256))[lane];
        a0 += ((bf2f(v0.x) + bf2f(v1.x)) + (bf2f(v2.x) + bf2f(v3.x)))
            + ((bf2f(v4.x) + bf2f(v5.x)) + (bf2f(v6.x) + bf2f(v7.x)));
        a1 += ((bf2f(v0.y) + bf2f(v1.y)) + (bf2f(v2.y) + bf2f(v3.y)))
            + ((bf2f(v4.y) + bf2f(v5.y)) + (bf2f(v6.y) + bf2f(v7.y)));
        a2 += ((bf2f(v0.z) + bf2f(v1.z)) + (bf2f(v2.z) + bf2f(v3.z)))
            + ((bf2f(v4.z) + bf2f(v5.z)) + (bf2f(v6.z) + bf2f(v7.z)));
        a3 += ((bf2f(v0.w) + bf2f(v1.w)) + (bf2f(v2.w) + bf2f(v3.w)))
            + ((bf2f(v4.w) + bf2f(v5.w)) + (bf2f(v6.w) + bf2f(v7.w)));
      }
      for (; j < chunk; ++j){
        int s = __builtin_amdgcn_readlane(myc, j);
        ushort4 v = ((const ushort4*)(hs + (size_t)s * 256))[lane];
        a0 += bf2f(v.x); a1 += bf2f(v.y); a2 += bf2f(v.z); a3 += bf2f(v.w);
      }
    }
    float dn = dinv[n];
    ushort4 o;
    o.x = f2bf(dn * a0 + bb.x);
    o.y = f2bf(dn * a1 + bb.y);
    o.z = f2bf(dn * a2 + bb.z);
    o.w = f2bf(dn * a3 + bb.w);
    ((ushort4*)h1)[(size_t)n * 64 + lane] = o;
  }
}

// ---------------- aggregation 2: persistent waves, width 128, fp32 out ----------------
__global__ __launch_bounds__(256) void k_agg2(const ushort* __restrict__ h2, const int* __restrict__ rs,
    const int* __restrict__ csrc, const float* __restrict__ dinv, const float* __restrict__ b2,
    float* __restrict__ out, int N){
  const int lane = threadIdx.x & 63;
  const int wid = (blockIdx.x * 256 + threadIdx.x) >> 6;
  const int nw = (AGG_BLOCKS * 256) >> 6;
  const float2 bb = ((const float2*)b2)[lane];

  for (int n = wid; n < N; n += nw){
    uint sv = ((const uint*)(h2 + (size_t)n * 128))[lane];
    float a0 = bf2f((unsigned short)(sv & 0xFFFF));
    float a1 = bf2f((unsigned short)(sv >> 16));
    int e0 = rs[n], deg = rs[n + 1] - e0;

    for (int c = 0; c < deg; c += 64){
      int chunk = deg - c; if (chunk > 64) chunk = 64;
      int myc = 0;
      if (lane < chunk) myc = csrc[e0 + c + lane];
      int j = 0;
      for (; j + 8 <= chunk; j += 8){
        int s0 = __builtin_amdgcn_readlane(myc, j);
        int s1 = __builtin_amdgcn_readlane(myc, j + 1);
        int s2 = __builtin_amdgcn_readlane(myc, j + 2);
        int s3 = __builtin_amdgcn_readlane(myc, j + 3);
        int s4 = __builtin_amdgcn_readlane(myc, j + 4);
        int s5 = __builtin_amdgcn_readlane(myc, j + 5);
        int s6 = __builtin_amdgcn_readlane(myc, j + 6);
        int s7 = __builtin_amdgcn_readlane(myc, j + 7);
        uint v0 = ((const uint*)(h2 + (size_t)s0 * 128))[lane];
        uint v1 = ((const uint*)(h2 + (size_t)s1 * 128))[lane];
        uint v2 = ((const uint*)(h2 + (size_t)s2 * 128))[lane];
        uint v3 = ((const uint*)(h2 + (size_t)s3 * 128))[lane];
        uint v4 = ((const uint*)(h2 + (size_t)s4 * 128))[lane];
        uint v5 = ((const uint*)(h2 + (size_t)s5 * 128))[lane];
        uint v6 = ((const uint*)(h2 + (size_t)s6 * 128))[lane];
        uint v7 = ((const uint*)(h2 + (size_t)s7 * 128))[lane];
        a0 += ((bf2f((unsigned short)(v0 & 0xFFFF)) + bf2f((unsigned short)(v1 & 0xFFFF)))
             + (bf2f((unsigned short)(v2 & 0xFFFF)) + bf2f((unsigned short)(v3 & 0xFFFF))))
            + ((bf2f((unsigned short)(v4 & 0xFFFF)) + bf2f((unsigned short)(v5 & 0xFFFF)))
             + (bf2f((unsigned short)(v6 & 0xFFFF)) + bf2f((unsigned short)(v7 & 0xFFFF))));
        a1 += ((bf2f((unsigned short)(v0 >> 16)) + bf2f((unsigned short)(v1 >> 16)))
             + (bf2f((unsigned short)(v2 >> 16)) + bf2f((unsigned short)(v3 >> 16))))
            + ((bf2f((unsigned short)(v4 >> 16)) + bf2f((unsigned short)(v5 >> 16)))
             + (bf2f((unsigned short)(v6 >> 16)) + bf2f((unsigned short)(v7 >> 16))));
      }
      for (; j < chunk; ++j){
        int s = __builtin_amdgcn_readlane(myc, j);
        uint v = ((const uint*)(h2 + (size_t)s * 128))[lane];
        a0 += bf2f((unsigned short)(v & 0xFFFF));
        a1 += bf2f((unsigned short)(v >> 16));
      }
    }
    float dn = dinv[n];
    float2 r; r.x = dn * a0 + bb.x; r.y = dn * a1 + bb.y;
    ((float2*)out)[(size_t)n * 64 + lane] = r;
  }
}

// ---------------- BatchNorm stats from bf16 h1 ----------------
__global__ void k_bnstats(const ushort* __restrict__ h1, float* __restrict__ sums,
                          float* __restrict__ sqs, int N){
  int cp = threadIdx.x & 127, ro = threadIdx.x >> 7;   // column pair, row half
  const uint* hv = (const uint*)h1;
  float s0 = 0.f, s1 = 0.f, q0 = 0.f, q1 = 0.f;
  for (int r = blockIdx.x * 2 + ro; r < N; r += gridDim.x * 2){
    uint v = hv[(size_t)r * 128 + cp];
    float x0 = bf2f((unsigned short)(v & 0xFFFF));
    float x1 = bf2f((unsigned short)(v >> 16));
    s0 += x0; q0 += x0 * x0;
    s1 += x1; q1 += x1 * x1;
  }
  atomicAdd(&sums[2 * cp],     s0);
  atomicAdd(&sums[2 * cp + 1], s1);
  atomicAdd(&sqs[2 * cp],      q0);
  atomicAdd(&sqs[2 * cp + 1],  q1);
}

// ---------------- BN finalize + apply + PReLU + bf16 cast ----------------
__global__ void k_prelu(const ushort* __restrict__ h1, const float* __restrict__ sums,
                        const float* __restrict__ sqs, const float* __restrict__ gamma,
                        const float* __restrict__ beta, const float* __restrict__ aP,
                        ushort* __restrict__ P, int N, int NP){
  int idx = blockIdx.x * 256 + threadIdx.x;   // NP*128 uint pairs
  int row = idx >> 7, cp = idx & 127;
  if (row >= NP) return;
  uint o = 0;
  if (row < N){
    int c0 = 2 * cp;
    float inv = 1.0f / (float)N;
    float m0 = sums[c0] * inv,     m1 = sums[c0 + 1] * inv;
    float v0 = sqs[c0] * inv - m0 * m0, v1 = sqs[c0 + 1] * inv - m1 * m1;
    float sc0 = gamma[c0] * rsqrtf(v0 + 1e-5f);
    float sc1 = gamma[c0 + 1] * rsqrtf(v1 + 1e-5f);
    float sh0 = beta[c0] - m0 * sc0;
    float sh1 = beta[c0 + 1] - m1 * sc1;
    uint v = ((const uint*)h1)[(size_t)row * 128 + cp];
    float aa = aP[0];
    float x0 = bf2f((unsigned short)(v & 0xFFFF)) * sc0 + sh0;
    float x1 = bf2f((unsigned short)(v >> 16)) * sc1 + sh1;
    x0 = x0 > 0.f ? x0 : aa * x0;
    x1 = x1 > 0.f ? x1 : aa * x1;
    o = (uint)f2bf(x0) | ((uint)f2bf(x1) << 16);
  }
  ((uint*)P)[idx] = o;
}

extern "C" void kernel_launch(void* const* d_in, const int* in_sizes, int n_in,
                              void* d_out, int out_size, void* d_ws, size_t ws_size,
                              hipStream_t stream){
  const float* x  = (const float*)d_in[0];
  const void*  ei = d_in[1];
  const float* W1 = (const float*)d_in[2];
  const float* b1 = (const float*)d_in[3];
  const float* W2 = (const float*)d_in[4];
  const float* b2 = (const float*)d_in[5];
  const float* gm = (const float*)d_in[6];
  const float* bt = (const float*)d_in[7];
  const float* aP = (const float*)d_in[8];
  float* out = (float*)d_out;

  const int N = in_sizes[0] / IN_DIM;          // 100000
  const long long E = in_sizes[1] / 2;         // 1600000
  const int NP = ((N + 127) / 128) * 128;      // 100096

  char* w = (char*)d_ws;
  size_t off = 0;
  auto carve = [&](size_t bytes) -> char* {
    char* p = w + off;
    off += (bytes + 255) & ~(size_t)255;
    return p;
  };
  ushort* xb  = (ushort*)carve((size_t)NP * 256 * 2);  // x bf16; reused for P
  ushort* hb  = (ushort*)carve((size_t)NP * 256 * 2);  // hs bf16; reused for h2s
  ushort* h1b = (ushort*)carve((size_t)NP * 256 * 2);  // h1 bf16
  ushort* W1t = (ushort*)carve(256 * 256 * 2);
  ushort* W2t = (ushort*)carve(128 * 256 * 2);
  int*   cnt  = (int*)  carve((size_t)N * 4);
  int*   rs   = (int*)  carve((size_t)(N + 1) * 4);
  int*   fill = (int*)  carve((size_t)N * 4);
  int*   csrc = (int*)  carve((size_t)E * 4);
  float* dinv = (float*)carve((size_t)N * 4);
  int*   bsum = (int*)  carve(512);
  int*   boff = (int*)  carve(512);
  float* sums = (float*)carve(1024);
  float* sqs  = (float*)carve(1024);
  int*   flag = (int*)  carve(256);

  const int NB1 = (N + 1023) / 1024;
  const int egrid = (int)((E + 255) / 256);
  const int prep_grid = (NP * 64 + 256 * 256 + 128 * 256 + 255) / 256;

  k_detect<<<1, 256, 0, stream>>>(ei, E, N, flag);
  hipMemsetAsync(cnt, 0, (size_t)N * 4, stream);
  k_prep<<<prep_grid, 256, 0, stream>>>(x, xb, W1, W1t, W2, W2t, N, NP);
  k_hist<<<egrid, 256, 0, stream>>>(ei, E, flag, cnt);
  k_scan1<<<NB1, 1024, 0, stream>>>(cnt, rs, bsum, dinv, fill, N);
  k_scan2<<<1, 128, 0, stream>>>(bsum, boff, NB1, rs, N, sums, sqs);
  k_scan3<<<NB1, 1024, 0, stream>>>(rs, boff, N);
  k_scatter<<<egrid, 256, 0, stream>>>(ei, E, flag, rs, fill, csrc);

  k_gemm<<<dim3(NP / 128, 2), 256, 0, stream>>>(xb, W1t, hb, dinv, N, 256);
  k_agg1<<<AGG_BLOCKS, 256, 0, stream>>>(hb, rs, csrc, dinv, b1, h1b, N);
  k_bnstats<<<256, 256, 0, stream>>>(h1b, sums, sqs, N);
  k_prelu<<<(NP * 128 + 255) / 256, 256, 0, stream>>>(h1b, sums, sqs, gm, bt, aP, xb, N, NP);
  k_gemm<<<dim3(NP / 128, 1), 256, 0, stream>>>(xb, W2t, hb, dinv, N, 128);
  k_agg2<<<AGG_BLOCKS, 256, 0, stream>>>(hb, rs, csrc, dinv, b2, out, N);
}

// Round 4
// 638.497 us; speedup vs baseline: 1.0721x; 1.0721x over previous
//
#include <hip/hip_runtime.h>
#include <hip/hip_bf16.h>
#include <stdint.h>

#define IN_DIM 256

typedef __attribute__((ext_vector_type(8))) short short8;
typedef __attribute__((ext_vector_type(4))) float f32x4;

__device__ __forceinline__ float bf2f(unsigned short u){
  return __uint_as_float(((unsigned int)u) << 16);
}
__device__ __forceinline__ unsigned short f2bf(float f){
  unsigned int u = __float_as_uint(f);
  u = u + 0x7FFFu + ((u >> 16) & 1u);
  return (unsigned short)(u >> 16);
}

#if __has_builtin(__builtin_amdgcn_cvt_f32_ubyte0)
__device__ __forceinline__ float ub0(uint v){ return __builtin_amdgcn_cvt_f32_ubyte0(v); }
__device__ __forceinline__ float ub1(uint v){ return __builtin_amdgcn_cvt_f32_ubyte1(v); }
__device__ __forceinline__ float ub2(uint v){ return __builtin_amdgcn_cvt_f32_ubyte2(v); }
__device__ __forceinline__ float ub3(uint v){ return __builtin_amdgcn_cvt_f32_ubyte3(v); }
#else
__device__ __forceinline__ float ub0(uint v){ return (float)(v & 0xFF); }
__device__ __forceinline__ float ub1(uint v){ return (float)((v >> 8) & 0xFF); }
__device__ __forceinline__ float ub2(uint v){ return (float)((v >> 16) & 0xFF); }
__device__ __forceinline__ float ub3(uint v){ return (float)(v >> 24); }
#endif

// ---------------- edge dtype detection (int64 vs int32) ----------------
__global__ void k_detect(const void* ei, long long E, int N, int* flag){
  __shared__ int bad;
  if (threadIdx.x == 0) bad = 0;
  __syncthreads();
  const long long* p = (const long long*)ei;
  long long stride = E / 1024; if (stride < 1) stride = 1;
  for (int i = threadIdx.x; i < 1024; i += blockDim.x){
    long long idx = (long long)i * stride;
    if (idx >= E) break;
    long long v = p[idx];
    if (v < 0 || v >= (long long)N) atomicOr(&bad, 1);
  }
  __syncthreads();
  if (threadIdx.x == 0) flag[0] = bad ? 0 : 1;  // 1 = int64 data
}

__device__ __forceinline__ int edge_at(const void* ei, long long i, int f64){
  if (f64) return (int)((const long long*)ei)[i];
  return ((const int*)ei)[i];
}

// ---------------- CSR build ----------------
__global__ void k_hist(const void* ei, long long E, const int* flag, int* cnt){
  long long e = (long long)blockIdx.x * blockDim.x + threadIdx.x;
  if (e < E){
    int f = flag[0];
    int d = edge_at(ei, E + e, f);
    atomicAdd(&cnt[d], 1);
  }
}

// scan1 also produces dinv and zeroes fill
__global__ void k_scan1(const int* cnt, int* rs, int* bsum, float* dinv, int* fill, int N){
  __shared__ int sh[1024];
  int i = blockIdx.x * 1024 + threadIdx.x;
  int v = (i < N) ? cnt[i] : 0;
  sh[threadIdx.x] = v;
  __syncthreads();
  for (int o = 1; o < 1024; o <<= 1){
    int x = (threadIdx.x >= o) ? sh[threadIdx.x - o] : 0;
    __syncthreads();
    sh[threadIdx.x] += x;
    __syncthreads();
  }
  if (i < N){
    rs[i] = sh[threadIdx.x] - v;          // exclusive
    dinv[i] = rsqrtf((float)v + 1.0f);
    fill[i] = 0;
  }
  if (threadIdx.x == 1023) bsum[blockIdx.x] = sh[1023];
}

// scan2 also zeroes BN accumulators
__global__ void k_scan2(const int* bsum, int* boff, int nb, int* rs, int N,
                        float* sums, float* sqs){
  __shared__ int sh[128];
  int t = threadIdx.x;
  int v = (t < nb) ? bsum[t] : 0;
  sh[t] = v;
  __syncthreads();
  for (int o = 1; o < 128; o <<= 1){
    int x = (t >= o) ? sh[t - o] : 0;
    __syncthreads();
    sh[t] += x;
    __syncthreads();
  }
  boff[t] = sh[t] - v;
  if (t == 127) rs[N] = sh[127];
  sums[t] = 0.f; sums[t + 128] = 0.f;
  sqs[t]  = 0.f; sqs[t + 128]  = 0.f;
}

__global__ void k_scan3(int* rs, const int* boff, int N){
  int i = blockIdx.x * 1024 + threadIdx.x;
  if (i < N) rs[i] += boff[blockIdx.x];
}

__global__ void k_scatter(const void* ei, long long E, const int* flag, const int* rs,
                          int* fill, int* csrc){
  long long e = (long long)blockIdx.x * blockDim.x + threadIdx.x;
  if (e < E){
    int f = flag[0];
    int s = edge_at(ei, e, f);
    int d = edge_at(ei, E + e, f);
    int pos = atomicAdd(&fill[d], 1);
    csrc[rs[d] + pos] = s;
  }
}

// ---------------- fused conversions: xb=bf16(x), W1t, W2t transposed bf16 ----------------
__global__ void k_prep(const float* __restrict__ x, ushort* __restrict__ xb,
                       const float* __restrict__ W1, ushort* __restrict__ W1t,
                       const float* __restrict__ W2, ushort* __restrict__ W2t,
                       int N, int NP){
  int idx = blockIdx.x * 256 + threadIdx.x;
  int nxq = NP * 64;                        // ushort4 groups in xb
  if (idx < nxq){
    int row = idx >> 6, q = idx & 63;
    ushort4 o = {0, 0, 0, 0};
    if (row < N){
      float4 v = ((const float4*)x)[(size_t)row * 64 + q];
      o.x = f2bf(v.x); o.y = f2bf(v.y); o.z = f2bf(v.z); o.w = f2bf(v.w);
    }
    ((ushort4*)xb)[idx] = o;
  } else {
    int j = idx - nxq;
    if (j < 256 * 256){                     // W1t[n*256+k] = W1[k*256+n]
      int n = j >> 8, k = j & 255;
      W1t[j] = f2bf(W1[(size_t)k * 256 + n]);
    } else {
      j -= 65536;
      if (j < 128 * 256){                   // W2t[n*256+k] = W2[k*128+n]
        int n = j >> 8, k = j & 255;
        W2t[j] = f2bf(W2[(size_t)k * 128 + n]);
      }
    }
  }
}

// ---------------- GEMM: C[M,Nc] = dinv[row] * (A[M,256] @ Bt[Nc,256]^T)  bf16 out ----------------
__global__ __launch_bounds__(256) void k_gemm(const ushort* __restrict__ A,
                                              const ushort* __restrict__ Bt,
                                              ushort* __restrict__ C,
                                              const float* __restrict__ dinv,
                                              int N, int Nc){
  __shared__ ushort As[128 * 64];
  __shared__ ushort Bs[128 * 64];
  const int tid = threadIdx.x;
  const int wave = tid >> 6, lane = tid & 63;
  const long long row0 = (long long)blockIdx.x * 128;
  const int col0 = blockIdx.y * 128;
  const int lr = lane >> 3, lc = lane & 7;
  const int mrow = ((wave & 1) << 6) + (lane & 15);
  const int ncol = ((wave >> 1) << 6) + (lane & 15);

  f32x4 acc[4][4];
  #pragma unroll
  for (int i = 0; i < 4; ++i)
    #pragma unroll
    for (int j = 0; j < 4; ++j)
      acc[i][j] = (f32x4){0.f, 0.f, 0.f, 0.f};

  const ushort* gA = A + (row0 + wave * 32 + lr) * 256 + lc * 8;
  const ushort* gB = Bt + ((long long)(col0 + wave * 32 + lr)) * 256 + lc * 8;
  ushort* lA = As + wave * 2048;
  ushort* lB = Bs + wave * 2048;

  #pragma unroll
  for (int kt = 0; kt < 4; ++kt){
    #pragma unroll
    for (int i = 0; i < 4; ++i){
      __builtin_amdgcn_global_load_lds(
          (const __attribute__((address_space(1))) void*)(gA + kt * 64 + i * 8 * 256),
          (__attribute__((address_space(3))) void*)(lA + i * 512), 16, 0, 0);
      __builtin_amdgcn_global_load_lds(
          (const __attribute__((address_space(1))) void*)(gB + kt * 64 + i * 8 * 256),
          (__attribute__((address_space(3))) void*)(lB + i * 512), 16, 0, 0);
    }
    __syncthreads();
    #pragma unroll
    for (int ks = 0; ks < 2; ++ks){
      const int kb = ks * 32 + ((lane >> 4) << 3);
      short8 af[4], bfv[4];
      #pragma unroll
      for (int i = 0; i < 4; ++i) af[i] = *(const short8*)(As + (mrow + i * 16) * 64 + kb);
      #pragma unroll
      for (int j = 0; j < 4; ++j) bfv[j] = *(const short8*)(Bs + (ncol + j * 16) * 64 + kb);
      #pragma unroll
      for (int i = 0; i < 4; ++i)
        #pragma unroll
        for (int j = 0; j < 4; ++j)
          acc[i][j] = __builtin_amdgcn_mfma_f32_16x16x32_bf16(af[i], bfv[j], acc[i][j], 0, 0, 0);
    }
    __syncthreads();
  }

  const int rbase = ((wave & 1) << 6) + ((lane >> 4) << 2);
  const int cb = col0 + ((wave >> 1) << 6) + (lane & 15);
  #pragma unroll
  for (int i = 0; i < 4; ++i)
    #pragma unroll
    for (int r = 0; r < 4; ++r){
      long long row = row0 + rbase + i * 16 + r;
      float sc = (row < N) ? dinv[row] : 0.f;
      #pragma unroll
      for (int j = 0; j < 4; ++j)
        C[row * Nc + cb + j * 16] = f2bf(sc * acc[i][j][r]);
    }
}

// ---------------- row quantize: bf16 256-wide -> int8(+128 bias) + fp32 scale ----------------
__global__ __launch_bounds__(256) void k_quant1(const ushort* __restrict__ hb,
    uint* __restrict__ q, float* __restrict__ sc, int N){
  int lane = threadIdx.x & 63;
  int r = blockIdx.x * 4 + (threadIdx.x >> 6);
  if (r >= N) return;
  ushort4 v = ((const ushort4*)hb)[(size_t)r * 64 + lane];
  float f0 = bf2f(v.x), f1 = bf2f(v.y), f2 = bf2f(v.z), f3 = bf2f(v.w);
  float m = fmaxf(fmaxf(fabsf(f0), fabsf(f1)), fmaxf(fabsf(f2), fabsf(f3)));
  #pragma unroll
  for (int o = 32; o >= 1; o >>= 1) m = fmaxf(m, __shfl_xor(m, o, 64));
  float scale = m * (1.0f / 127.0f);
  float inv = (m > 0.f) ? 127.0f / m : 0.f;
  uint b0 = (uint)(int)(rintf(f0 * inv) + 128.0f);
  uint b1 = (uint)(int)(rintf(f1 * inv) + 128.0f);
  uint b2 = (uint)(int)(rintf(f2 * inv) + 128.0f);
  uint b3 = (uint)(int)(rintf(f3 * inv) + 128.0f);
  q[(size_t)r * 64 + lane] = b0 | (b1 << 8) | (b2 << 16) | (b3 << 24);
  if (lane == 0) sc[r] = scale;
}

// ---------------- row quantize: bf16 128-wide -> int8 + scale ----------------
__global__ __launch_bounds__(256) void k_quant2(const ushort* __restrict__ hb,
    ushort* __restrict__ q, float* __restrict__ sc, int N){
  int lane = threadIdx.x & 63;
  int r = blockIdx.x * 4 + (threadIdx.x >> 6);
  if (r >= N) return;
  uint v = ((const uint*)hb)[(size_t)r * 64 + lane];
  float f0 = bf2f((unsigned short)(v & 0xFFFF));
  float f1 = bf2f((unsigned short)(v >> 16));
  float m = fmaxf(fabsf(f0), fabsf(f1));
  #pragma unroll
  for (int o = 32; o >= 1; o >>= 1) m = fmaxf(m, __shfl_xor(m, o, 64));
  float scale = m * (1.0f / 127.0f);
  float inv = (m > 0.f) ? 127.0f / m : 0.f;
  uint b0 = (uint)(int)(rintf(f0 * inv) + 128.0f);
  uint b1 = (uint)(int)(rintf(f1 * inv) + 128.0f);
  q[(size_t)r * 64 + lane] = (ushort)(b0 | (b1 << 8));
  if (lane == 0) sc[r] = scale;
}

// ---------------- aggregation 1: int8 gather, fused BN stats, bf16 out ----------------
__global__ __launch_bounds__(256) void k_agg1(const uint* __restrict__ q, const float* __restrict__ sc,
    const int* __restrict__ rs, const int* __restrict__ csrc, const float* __restrict__ b1,
    ushort* __restrict__ h1, float* __restrict__ sums, float* __restrict__ sqs,
    int N, int nblocks){
  __shared__ float red[4 * 512];
  const int lane = threadIdx.x & 63;
  const int wid = (blockIdx.x * 256 + threadIdx.x) >> 6;
  const int nw = (nblocks * 256) >> 6;
  const float4 bb = ((const float4*)b1)[lane];
  float st0 = 0.f, st1 = 0.f, st2 = 0.f, st3 = 0.f;
  float sq0 = 0.f, sq1 = 0.f, sq2 = 0.f, sq3 = 0.f;

  for (int n = wid; n < N; n += nw){
    int e = rs[n], end = rs[n + 1];
    float dn = rsqrtf((float)(end - e) + 1.0f);
    float scn = sc[n];
    uint v = q[(size_t)n * 64 + lane];
    float ssum = scn;
    float a0 = scn * ub0(v), a1 = scn * ub1(v), a2 = scn * ub2(v), a3 = scn * ub3(v);
    for (; e + 4 <= end; e += 4){
      int s0 = csrc[e], s1 = csrc[e + 1], s2 = csrc[e + 2], s3 = csrc[e + 3];
      float c0 = sc[s0], c1 = sc[s1], c2 = sc[s2], c3 = sc[s3];
      uint v0 = q[(size_t)s0 * 64 + lane];
      uint v1 = q[(size_t)s1 * 64 + lane];
      uint v2 = q[(size_t)s2 * 64 + lane];
      uint v3 = q[(size_t)s3 * 64 + lane];
      ssum += (c0 + c1) + (c2 + c3);
      a0 += (c0 * ub0(v0) + c1 * ub0(v1)) + (c2 * ub0(v2) + c3 * ub0(v3));
      a1 += (c0 * ub1(v0) + c1 * ub1(v1)) + (c2 * ub1(v2) + c3 * ub1(v3));
      a2 += (c0 * ub2(v0) + c1 * ub2(v1)) + (c2 * ub2(v2) + c3 * ub2(v3));
      a3 += (c0 * ub3(v0) + c1 * ub3(v1)) + (c2 * ub3(v2) + c3 * ub3(v3));
    }
    for (; e < end; ++e){
      int s = csrc[e];
      float c = sc[s];
      uint vv = q[(size_t)s * 64 + lane];
      ssum += c;
      a0 += c * ub0(vv); a1 += c * ub1(vv); a2 += c * ub2(vv); a3 += c * ub3(vv);
    }
    float corr = -128.0f * ssum;
    float h0 = dn * (a0 + corr) + bb.x;
    float h1v = dn * (a1 + corr) + bb.y;
    float h2 = dn * (a2 + corr) + bb.z;
    float h3 = dn * (a3 + corr) + bb.w;
    st0 += h0; st1 += h1v; st2 += h2; st3 += h3;
    sq0 += h0 * h0; sq1 += h1v * h1v; sq2 += h2 * h2; sq3 += h3 * h3;
    ushort4 o;
    o.x = f2bf(h0); o.y = f2bf(h1v); o.z = f2bf(h2); o.w = f2bf(h3);
    ((ushort4*)h1)[(size_t)n * 64 + lane] = o;
  }

  // block-reduce stats then atomics
  int wv = threadIdx.x >> 6;
  int f = lane * 4;
  red[wv * 512 + f]     = st0; red[wv * 512 + f + 1] = st1;
  red[wv * 512 + f + 2] = st2; red[wv * 512 + f + 3] = st3;
  __syncthreads();
  // reuse: second half for squares via two-phase
  float v0s = red[threadIdx.x] + red[512 + threadIdx.x] + red[1024 + threadIdx.x] + red[1536 + threadIdx.x];
  float v1s = (threadIdx.x < 256) ? 0.f : 0.f;
  __syncthreads();
  red[wv * 512 + f]     = sq0; red[wv * 512 + f + 1] = sq1;
  red[wv * 512 + f + 2] = sq2; red[wv * 512 + f + 3] = sq3;
  __syncthreads();
  float v0q = red[threadIdx.x] + red[512 + threadIdx.x] + red[1024 + threadIdx.x] + red[1536 + threadIdx.x];
  (void)v1s;
  if (threadIdx.x < 256){
    atomicAdd(&sums[threadIdx.x], v0s);
    atomicAdd(&sqs[threadIdx.x], v0q);
  }
}

// ---------------- aggregation 2: int8 gather, fp32 out ----------------
__global__ __launch_bounds__(256) void k_agg2(const ushort* __restrict__ q, const float* __restrict__ sc,
    const int* __restrict__ rs, const int* __restrict__ csrc, const float* __restrict__ b2,
    float* __restrict__ out, int N, int nblocks){
  const int lane = threadIdx.x & 63;
  const int wid = (blockIdx.x * 256 + threadIdx.x) >> 6;
  const int nw = (nblocks * 256) >> 6;
  const float2 bb = ((const float2*)b2)[lane];

  for (int n = wid; n < N; n += nw){
    int e = rs[n], end = rs[n + 1];
    float dn = rsqrtf((float)(end - e) + 1.0f);
    float scn = sc[n];
    uint v = (uint)q[(size_t)n * 64 + lane];
    float ssum = scn;
    float a0 = scn * ub0(v), a1 = scn * ub1(v);
    for (; e + 4 <= end; e += 4){
      int s0 = csrc[e], s1 = csrc[e + 1], s2 = csrc[e + 2], s3 = csrc[e + 3];
      float c0 = sc[s0], c1 = sc[s1], c2 = sc[s2], c3 = sc[s3];
      uint v0 = (uint)q[(size_t)s0 * 64 + lane];
      uint v1 = (uint)q[(size_t)s1 * 64 + lane];
      uint v2 = (uint)q[(size_t)s2 * 64 + lane];
      uint v3 = (uint)q[(size_t)s3 * 64 + lane];
      ssum += (c0 + c1) + (c2 + c3);
      a0 += (c0 * ub0(v0) + c1 * ub0(v1)) + (c2 * ub0(v2) + c3 * ub0(v3));
      a1 += (c0 * ub1(v0) + c1 * ub1(v1)) + (c2 * ub1(v2) + c3 * ub1(v3));
    }
    for (; e < end; ++e){
      int s = csrc[e];
      float c = sc[s];
      uint vv = (uint)q[(size_t)s * 64 + lane];
      ssum += c;
      a0 += c * ub0(vv); a1 += c * ub1(vv);
    }
    float corr = -128.0f * ssum;
    float2 r;
    r.x = dn * (a0 + corr) + bb.x;
    r.y = dn * (a1 + corr) + bb.y;
    ((float2*)out)[(size_t)n * 64 + lane] = r;
  }
}

// ---------------- BN finalize + apply + PReLU + bf16 cast ----------------
__global__ void k_prelu(const ushort* __restrict__ h1, const float* __restrict__ sums,
                        const float* __restrict__ sqs, const float* __restrict__ gamma,
                        const float* __restrict__ beta, const float* __restrict__ aP,
                        ushort* __restrict__ P, int N, int NP){
  int idx = blockIdx.x * 256 + threadIdx.x;   // NP*128 uint pairs
  int row = idx >> 7, cp = idx & 127;
  if (row >= NP) return;
  uint o = 0;
  if (row < N){
    int c0 = 2 * cp;
    float inv = 1.0f / (float)N;
    float m0 = sums[c0] * inv,     m1 = sums[c0 + 1] * inv;
    float v0 = sqs[c0] * inv - m0 * m0, v1 = sqs[c0 + 1] * inv - m1 * m1;
    float sc0 = gamma[c0] * rsqrtf(v0 + 1e-5f);
    float sc1 = gamma[c0 + 1] * rsqrtf(v1 + 1e-5f);
    float sh0 = beta[c0] - m0 * sc0;
    float sh1 = beta[c0 + 1] - m1 * sc1;
    uint v = ((const uint*)h1)[(size_t)row * 128 + cp];
    float aa = aP[0];
    float x0 = bf2f((unsigned short)(v & 0xFFFF)) * sc0 + sh0;
    float x1 = bf2f((unsigned short)(v >> 16)) * sc1 + sh1;
    x0 = x0 > 0.f ? x0 : aa * x0;
    x1 = x1 > 0.f ? x1 : aa * x1;
    o = (uint)f2bf(x0) | ((uint)f2bf(x1) << 16);
  }
  ((uint*)P)[idx] = o;
}

extern "C" void kernel_launch(void* const* d_in, const int* in_sizes, int n_in,
                              void* d_out, int out_size, void* d_ws, size_t ws_size,
                              hipStream_t stream){
  const float* x  = (const float*)d_in[0];
  const void*  ei = d_in[1];
  const float* W1 = (const float*)d_in[2];
  const float* b1 = (const float*)d_in[3];
  const float* W2 = (const float*)d_in[4];
  const float* b2 = (const float*)d_in[5];
  const float* gm = (const float*)d_in[6];
  const float* bt = (const float*)d_in[7];
  const float* aP = (const float*)d_in[8];
  float* out = (float*)d_out;

  const int N = in_sizes[0] / IN_DIM;          // 100000
  const long long E = in_sizes[1] / 2;         // 1600000
  const int NP = ((N + 127) / 128) * 128;      // 100096

  char* w = (char*)d_ws;
  size_t off = 0;
  auto carve = [&](size_t bytes) -> char* {
    char* p = w + off;
    off += (bytes + 255) & ~(size_t)255;
    return p;
  };
  ushort* xb  = (ushort*)carve((size_t)NP * 256 * 2);  // x bf16; reused for P after agg1
  ushort* hb  = (ushort*)carve((size_t)NP * 256 * 2);  // GEMM1 out hs bf16; reused for GEMM2 out
  ushort* h1b = (ushort*)carve((size_t)NP * 256 * 2);  // h1 bf16; first half reused for q8b after prelu
  ushort* W1t = (ushort*)carve(256 * 256 * 2);
  ushort* W2t = (ushort*)carve(128 * 256 * 2);
  int*   cnt  = (int*)  carve((size_t)N * 4);
  int*   rs   = (int*)  carve((size_t)(N + 1) * 4);
  int*   fill = (int*)  carve((size_t)N * 4);
  int*   csrc = (int*)  carve((size_t)E * 4);
  float* dinv = (float*)carve((size_t)N * 4);
  float* sc1  = (float*)carve((size_t)N * 4);
  float* sc2  = (float*)carve((size_t)N * 4);
  int*   bsum = (int*)  carve(512);
  int*   boff = (int*)  carve(512);
  float* sums = (float*)carve(1024);
  float* sqs  = (float*)carve(1024);
  int*   flag = (int*)  carve(256);
  // aliased int8 tables (lifetimes verified stream-ordered):
  uint*   q8a = (uint*)xb;      // [N*64] dwords = 25.6 MB; dead before prelu overwrites xb
  ushort* q8b = (ushort*)h1b;   // [N*64] ushorts = 12.8 MB; h1b dead after prelu reads it

  const int NB1 = (N + 1023) / 1024;
  const int egrid = (int)((E + 255) / 256);
  const int prep_grid = (NP * 64 + 256 * 256 + 128 * 256 + 255) / 256;
  const int AGG1_BLOCKS = 1024, AGG2_BLOCKS = 2048;

  k_detect<<<1, 256, 0, stream>>>(ei, E, N, flag);
  hipMemsetAsync(cnt, 0, (size_t)N * 4, stream);
  k_prep<<<prep_grid, 256, 0, stream>>>(x, xb, W1, W1t, W2, W2t, N, NP);
  k_hist<<<egrid, 256, 0, stream>>>(ei, E, flag, cnt);
  k_scan1<<<NB1, 1024, 0, stream>>>(cnt, rs, bsum, dinv, fill, N);
  k_scan2<<<1, 128, 0, stream>>>(bsum, boff, NB1, rs, N, sums, sqs);
  k_scan3<<<NB1, 1024, 0, stream>>>(rs, boff, N);
  k_scatter<<<egrid, 256, 0, stream>>>(ei, E, flag, rs, fill, csrc);

  k_gemm<<<dim3(NP / 128, 2), 256, 0, stream>>>(xb, W1t, hb, dinv, N, 256);
  // NOTE: q8a aliases xb, but k_quant1 reads hb and writes q8a AFTER gemm1 consumed xb.
  k_quant1<<<(N + 3) / 4, 256, 0, stream>>>(hb, q8a, sc1, N);
  k_agg1<<<AGG1_BLOCKS, 256, 0, stream>>>(q8a, sc1, rs, csrc, b1, h1b, sums, sqs, N, AGG1_BLOCKS);
  k_prelu<<<(NP * 128 + 255) / 256, 256, 0, stream>>>(h1b, sums, sqs, gm, bt, aP, xb, N, NP);
  k_gemm<<<dim3(NP / 128, 1), 256, 0, stream>>>(xb, W2t, hb, dinv, N, 128);
  k_quant2<<<(N + 3) / 4, 256, 0, stream>>>(hb, q8b, sc2, N);
  k_agg2<<<AGG2_BLOCKS, 256, 0, stream>>>(q8b, sc2, rs, csrc, b2, out, N, AGG2_BLOCKS);
}